// Round 7
// baseline (355.520 us; speedup 1.0000x reference)
//
#include <hip/hip_runtime.h>
#include <hip/hip_bf16.h>

#define D_MODEL 512
#define NHEAD   8
#define DK      64
#define SEQ     4096
#define BATCH   2
#define NTOK    (BATCH * SEQ)

typedef __bf16 bf16;
typedef __bf16 bf16x4 __attribute__((ext_vector_type(4)));
typedef __bf16 bf16x8 __attribute__((ext_vector_type(8)));
typedef float  f32x4  __attribute__((ext_vector_type(4)));
typedef float  f32x16 __attribute__((ext_vector_type(16)));

#define MFMA16(a, b, c) __builtin_amdgcn_mfma_f32_16x16x32_bf16((a), (b), (c), 0, 0, 0)
#define MFMA32(a, b, c) __builtin_amdgcn_mfma_f32_32x32x16_bf16((a), (b), (c), 0, 0, 0)

// 0.125 (1/sqrt(dk)) * log2(e) folded into Q so softmax is exp2(s) directly.
#define QSCALE 0.18033688f

// ---------------------------------------------------------------------------
// Kernel 0: weight fp32 -> bf16 (wq, wk, wv, wo), one float4 per thread.
// ---------------------------------------------------------------------------
__global__ __launch_bounds__(256) void cvt_w(
    const float* __restrict__ wq, const float* __restrict__ wk,
    const float* __restrict__ wv, const float* __restrict__ wo,
    bf16* __restrict__ Wb)
{
    int i = blockIdx.x * 256 + threadIdx.x;          // 0..262143
    int m = i >> 16;                                 // matrix id
    int g = i & 65535;                               // float4 group
    const float* src = (m == 0) ? wq : (m == 1) ? wk : (m == 2) ? wv : wo;
    float4 x = *(const float4*)(src + (size_t)g * 4);
    bf16x4 y = {(bf16)x.x, (bf16)x.y, (bf16)x.z, (bf16)x.w};
    *(bf16x4*)(Wb + (size_t)m * D_MODEL * D_MODEL + (size_t)g * 4) = y;
}

// ---------------------------------------------------------------------------
// Kernel 1: fused QKV projection, 128x128 tile, BK=64.
// p = 0:Q (pre-scaled by QSCALE), 1:K, 2:V.  W read from pre-cvt bf16 Wb.
// V goes through an LDS transpose so the Vt[bh][d][s] store is coalesced.
// ---------------------------------------------------------------------------
__global__ __launch_bounds__(256, 3) void proj_qkv(
    const float* __restrict__ q, const float* __restrict__ k, const float* __restrict__ v,
    const bf16* __restrict__ Wb,
    const float* __restrict__ bq, const float* __restrict__ bk, const float* __restrict__ bv,
    bf16* __restrict__ Qh, bf16* __restrict__ Kh, bf16* __restrict__ Vt)
{
    const int p = blockIdx.z;
    const float* X    = (p == 0) ? q  : (p == 1) ? k  : v;
    const bf16*  W    = Wb + (size_t)p * D_MODEL * D_MODEL;
    const float* bias = (p == 0) ? bq : (p == 1) ? bk : bv;

    __shared__ union __align__(16) {
        struct { bf16 As[128][72]; bf16 Bs[128][72]; } g;
        bf16 T[128][136];   // V-transpose buffer
    } sm;

    const int m0   = blockIdx.x * 128;
    const int n0   = blockIdx.y * 128;
    const int tid  = threadIdx.x;
    const int lane = tid & 63;
    const int wave = tid >> 6;
    const int low4 = lane & 15;
    const int quad = lane >> 4;
    const int wm   = wave >> 1;
    const int wn   = wave & 1;

    int srow[8], sc4[8];
    for (int it = 0; it < 8; ++it) {
        int idx = tid + it * 256;          // 0..2047
        srow[it] = idx >> 4;               // 0..127
        sc4[it]  = (idx & 15) * 4;         // 0..60
    }
    int br[4], bc[4];
    for (int it = 0; it < 4; ++it) {
        int idx = tid + it * 256;          // 0..1023
        br[it] = idx >> 3;                 // 0..127
        bc[it] = (idx & 7) * 8;            // 0..56
    }

    float4 gA[8];
    bf16x8 gB[4];
    for (int it = 0; it < 8; ++it)
        gA[it] = *(const float4*)(X + (size_t)(m0 + srow[it]) * D_MODEL + sc4[it]);
    for (int it = 0; it < 4; ++it)
        gB[it] = *(const bf16x8*)(W + (size_t)(n0 + br[it]) * D_MODEL + bc[it]);

    f32x4 acc[4][4];
    for (int i = 0; i < 4; ++i)
        for (int j = 0; j < 4; ++j)
            acc[i][j] = f32x4{0.f, 0.f, 0.f, 0.f};

    for (int k0 = 0; k0 < D_MODEL; k0 += 64) {
        __syncthreads();
        for (int it = 0; it < 8; ++it) {
            bf16x4 wa = {(bf16)gA[it].x, (bf16)gA[it].y, (bf16)gA[it].z, (bf16)gA[it].w};
            *(bf16x4*)&sm.g.As[srow[it]][sc4[it]] = wa;
        }
        for (int it = 0; it < 4; ++it)
            *(bf16x8*)&sm.g.Bs[br[it]][bc[it]] = gB[it];
        __syncthreads();

        if (k0 + 64 < D_MODEL) {
            for (int it = 0; it < 8; ++it)
                gA[it] = *(const float4*)(X + (size_t)(m0 + srow[it]) * D_MODEL + k0 + 64 + sc4[it]);
            for (int it = 0; it < 4; ++it)
                gB[it] = *(const bf16x8*)(W + (size_t)(n0 + br[it]) * D_MODEL + k0 + 64 + bc[it]);
        }

        for (int ks = 0; ks < 2; ++ks) {
            bf16x8 a[4], b[4];
            for (int i = 0; i < 4; ++i)
                a[i] = *(const bf16x8*)&sm.g.As[wm * 64 + i * 16 + low4][ks * 32 + quad * 8];
            for (int j = 0; j < 4; ++j)
                b[j] = *(const bf16x8*)&sm.g.Bs[wn * 64 + j * 16 + low4][ks * 32 + quad * 8];
            for (int i = 0; i < 4; ++i)
                for (int j = 0; j < 4; ++j)
                    acc[i][j] = MFMA16(a[i], b[j], acc[i][j]);
        }
    }

    if (p < 2) {
        bf16* Out = (p == 0) ? Qh : Kh;
        const float sc = (p == 0) ? QSCALE : 1.0f;
        for (int j = 0; j < 4; ++j) {
            int col = n0 + wn * 64 + j * 16 + low4;
            float bcol = bias[col];
            for (int i = 0; i < 4; ++i)
                for (int r = 0; r < 4; ++r) {
                    int row = m0 + wm * 64 + i * 16 + quad * 4 + r;
                    Out[(size_t)row * D_MODEL + col] = (bf16)((acc[i][j][r] + bcol) * sc);
                }
        }
    } else {
        // V: transpose through LDS -> coalesced b128 stores to Vt[bh][d][s].
        __syncthreads();
        for (int j = 0; j < 4; ++j) {
            int col = n0 + wn * 64 + j * 16 + low4;
            float bcol = bias[col];
            for (int i = 0; i < 4; ++i)
                for (int r = 0; r < 4; ++r)
                    sm.T[wn * 64 + j * 16 + low4][wm * 64 + i * 16 + quad * 4 + r] =
                        (bf16)(acc[i][j][r] + bcol);
        }
        __syncthreads();
        const int bb = m0 >> 12;
        const int s0 = (m0 & 4095);
        for (int it = 0; it < 8; ++it) {
            int cc = it * 16 + (tid >> 4);   // 0..127 col-local
            int ml = (tid & 15) * 8;         // 0..120 m-local
            int col = n0 + cc;
            int hh = col >> 6, dd = col & 63;
            *(bf16x8*)&Vt[(((size_t)(bb * NHEAD + hh) * DK + dd) << 12) + s0 + ml] =
                *(const bf16x8*)&sm.T[cc][ml];
        }
    }
}

// ---------------------------------------------------------------------------
// Kernel 2: flash attention, 32x32x16 MFMA, 2 q-tiles per wave.
// Block = 256 threads = 4 waves = 2 q-halves x 2 key-halves; block covers
// 128 q-rows of one (b,h); phase = 128 keys.  kf/vf frags loaded once per
// phase and reused across both q-tiles (LDS bytes/FLOP cut ~28% vs 1-qt).
// Grid flat 512, XCD-swizzled: bh = (flat&7)*2 + (slot>>5) pins 2 K/V
// streams (2 MB) per XCD L2.  Fixed-reference softmax p = exp2(s).
// C/D layout (m74/m101): col=lane&31, row=(reg&3)+8*(reg>>2)+4*(lane>>5).
// ---------------------------------------------------------------------------
__global__ __launch_bounds__(256, 2) void attn(
    const bf16* __restrict__ Qh, const bf16* __restrict__ Kh,
    const bf16* __restrict__ Vt, bf16* __restrict__ O)
{
    __shared__ union __align__(16) {
        struct { bf16 Ks[128][72]; bf16 Vs[64][136]; } s;
        float Obuf[128][68];                 // kg-combine buffer (overlay)
    } sm;
    __shared__ bf16  Ps[4][2][32][72];       // per-wave, per-qt P round-trip
    __shared__ float Lbuf[2][2][32];

    const int flat = blockIdx.x;
    const int slot = flat >> 3;              // 0..63
    const int bh   = (flat & 7) * 2 + (slot >> 5);
    const int q0   = (slot & 31) * 128;
    const int b    = bh >> 3, h = bh & 7;
    const int tid  = threadIdx.x;
    const int lane = tid & 63;
    const int wave = tid >> 6;               // 0..3
    const int qp   = wave >> 1;              // q 64-half
    const int kg   = wave & 1;               // key 64-half
    const int m32  = lane & 31;
    const int hl   = lane >> 5;

    const bf16* Kbase = Kh + (size_t)b * SEQ * D_MODEL + h * DK;
    const bf16* Vbase = Vt + (size_t)bh * DK * SEQ;

    // Q B-frags, register-resident for whole kernel (2 q-tiles x 64 k)
    bf16x8 qf[2][4];
    for (int qt = 0; qt < 2; ++qt) {
        const bf16* Qrow = Qh + (size_t)(b * SEQ + q0 + qp * 64 + qt * 32 + m32) * D_MODEL + h * DK;
        for (int ks = 0; ks < 4; ++ks)
            qf[qt][ks] = *(const bf16x8*)(Qrow + ks * 16 + hl * 8);
    }

    float l[2] = {0.f, 0.f};
    f32x16 acc[2][2];
    for (int qt = 0; qt < 2; ++qt)
        for (int nt = 0; nt < 2; ++nt)
            for (int i = 0; i < 16; ++i) acc[qt][nt][i] = 0.f;

    int krr[4], kcc[4], vrr[4], vcc[4];
    for (int it = 0; it < 4; ++it) {
        int idx = tid + it * 256;            // 0..1023
        krr[it] = idx >> 3;  kcc[it] = (idx & 7) * 8;     // Ks: 128 x 64
        vrr[it] = idx >> 4;  vcc[it] = (idx & 15) * 8;    // Vs: 64 x 128
    }
    bf16x8 gk[4], gv[4];
    for (int it = 0; it < 4; ++it) {
        gk[it] = *(const bf16x8*)(Kbase + (size_t)krr[it] * D_MODEL + kcc[it]);
        gv[it] = *(const bf16x8*)(Vbase + (size_t)vrr[it] * SEQ + vcc[it]);
    }

    for (int t0 = 0; t0 < SEQ; t0 += 128) {
        __syncthreads();
        for (int it = 0; it < 4; ++it) {
            *(bf16x8*)&sm.s.Ks[krr[it]][kcc[it]] = gk[it];
            *(bf16x8*)&sm.s.Vs[vrr[it]][vcc[it]] = gv[it];
        }
        __syncthreads();

        if (t0 + 128 < SEQ) {
            for (int it = 0; it < 4; ++it) {
                gk[it] = *(const bf16x8*)(Kbase + (size_t)(t0 + 128 + krr[it]) * D_MODEL + kcc[it]);
                gv[it] = *(const bf16x8*)(Vbase + (size_t)vrr[it] * SEQ + t0 + 128 + vcc[it]);
            }
        }

        // ---- K frags once, reused by both q-tiles ----
        bf16x8 kf[2][4];
        for (int mt = 0; mt < 2; ++mt)
            for (int ks = 0; ks < 4; ++ks)
                kf[mt][ks] = *(const bf16x8*)&sm.s.Ks[kg * 64 + mt * 32 + m32][ks * 16 + hl * 8];

        for (int qt = 0; qt < 2; ++qt) {
            // S^T = K Q^T : lane holds S[q=m32][key rows in reg pattern]
            f32x16 sc[2];
            for (int mt = 0; mt < 2; ++mt) {
                for (int i = 0; i < 16; ++i) sc[mt][i] = 0.f;
                for (int ks = 0; ks < 4; ++ks)
                    sc[mt] = MFMA32(kf[mt][ks], qf[qt][ks], sc[mt]);
            }
            for (int mt = 0; mt < 2; ++mt)
                for (int g = 0; g < 4; ++g) {
                    float p0 = __builtin_amdgcn_exp2f(sc[mt][g * 4 + 0]);
                    float p1 = __builtin_amdgcn_exp2f(sc[mt][g * 4 + 1]);
                    float p2 = __builtin_amdgcn_exp2f(sc[mt][g * 4 + 2]);
                    float p3 = __builtin_amdgcn_exp2f(sc[mt][g * 4 + 3]);
                    l[qt] += (p0 + p1) + (p2 + p3);
                    bf16x4 pw = {(bf16)p0, (bf16)p1, (bf16)p2, (bf16)p3};
                    *(bf16x4*)&Ps[wave][qt][m32][mt * 32 + g * 8 + hl * 4] = pw;
                }
        }

        // ---- V frags once, reused by both q-tiles ----
        bf16x8 vf[2][4];
        for (int nt = 0; nt < 2; ++nt)
            for (int ks = 0; ks < 4; ++ks)
                vf[nt][ks] = *(const bf16x8*)&sm.s.Vs[nt * 32 + m32][kg * 64 + ks * 16 + hl * 8];

        for (int qt = 0; qt < 2; ++qt)
            for (int ks = 0; ks < 4; ++ks) {
                bf16x8 pf = *(const bf16x8*)&Ps[wave][qt][m32][ks * 16 + hl * 8];
                for (int nt = 0; nt < 2; ++nt)
                    acc[qt][nt] = MFMA32(pf, vf[nt][ks], acc[qt][nt]);
            }
    }

    // ---- combine key-halves + normalize + store ----
    for (int qt = 0; qt < 2; ++qt)
        l[qt] += __shfl_xor(l[qt], 32);
    __syncthreads();                         // Ks/Vs dead -> Obuf overlay safe
    if (kg == 1) {
        for (int qt = 0; qt < 2; ++qt) {
            for (int nt = 0; nt < 2; ++nt)
                for (int r = 0; r < 16; ++r) {
                    int qq = (r & 3) + 8 * (r >> 2) + 4 * hl;
                    sm.Obuf[qp * 64 + qt * 32 + qq][nt * 32 + m32] = acc[qt][nt][r];
                }
            if (hl == 0) Lbuf[qp][qt][m32] = l[qt];
        }
    }
    __syncthreads();
    if (kg == 0) {
        for (int qt = 0; qt < 2; ++qt) {
            float lt  = l[qt] + Lbuf[qp][qt][m32];
            float inv = 1.0f / lt;           // valid for q = m32
            for (int nt = 0; nt < 2; ++nt)
                for (int r = 0; r < 16; ++r) {
                    int qq = (r & 3) + 8 * (r >> 2) + 4 * hl;
                    float val = acc[qt][nt][r] + sm.Obuf[qp * 64 + qt * 32 + qq][nt * 32 + m32];
                    float iv  = __shfl(inv, qq);
                    O[(size_t)(b * SEQ + q0 + qp * 64 + qt * 32 + qq) * D_MODEL + h * DK + nt * 32 + m32] =
                        (bf16)(val * iv);
                }
        }
    }
}

// ---------------------------------------------------------------------------
// Kernel 3: output projection, 64x64 tile (1024 blocks -> 4/CU), bf16 W.
// ---------------------------------------------------------------------------
__global__ __launch_bounds__(256, 4) void proj_out(
    const bf16* __restrict__ Oin, const bf16* __restrict__ Wo,
    const float* __restrict__ bo, float* __restrict__ out)
{
    __shared__ bf16 As[64][72];
    __shared__ bf16 Bs[64][72];

    const int m0   = blockIdx.x * 64;
    const int n0   = blockIdx.y * 64;
    const int tid  = threadIdx.x;
    const int lane = tid & 63;
    const int wave = tid >> 6;
    const int low4 = lane & 15;
    const int quad = lane >> 4;
    const int wm   = wave >> 1;
    const int wn   = wave & 1;

    int arow[2], ag[2];
    for (int it = 0; it < 2; ++it) {
        int idx = tid + it * 256;
        arow[it] = idx >> 3;
        ag[it]   = (idx & 7) * 8;
    }

    bf16x8 gA[2], gB[2];
    for (int it = 0; it < 2; ++it) {
        gA[it] = *(const bf16x8*)(Oin + (size_t)(m0 + arow[it]) * D_MODEL + ag[it]);
        gB[it] = *(const bf16x8*)(Wo + (size_t)(n0 + arow[it]) * D_MODEL + ag[it]);
    }

    f32x4 acc[2][2];
    for (int i = 0; i < 2; ++i)
        for (int j = 0; j < 2; ++j)
            acc[i][j] = f32x4{0.f, 0.f, 0.f, 0.f};

    for (int k0 = 0; k0 < D_MODEL; k0 += 64) {
        __syncthreads();
        for (int it = 0; it < 2; ++it) {
            *(bf16x8*)&As[arow[it]][ag[it]] = gA[it];
            *(bf16x8*)&Bs[arow[it]][ag[it]] = gB[it];
        }
        __syncthreads();

        if (k0 + 64 < D_MODEL) {
            for (int it = 0; it < 2; ++it) {
                gA[it] = *(const bf16x8*)(Oin + (size_t)(m0 + arow[it]) * D_MODEL + k0 + 64 + ag[it]);
                gB[it] = *(const bf16x8*)(Wo + (size_t)(n0 + arow[it]) * D_MODEL + k0 + 64 + ag[it]);
            }
        }

        for (int ks = 0; ks < 2; ++ks) {
            bf16x8 a[2], b[2];
            for (int i = 0; i < 2; ++i)
                a[i] = *(const bf16x8*)&As[wm * 32 + i * 16 + low4][ks * 32 + quad * 8];
            for (int j = 0; j < 2; ++j)
                b[j] = *(const bf16x8*)&Bs[wn * 32 + j * 16 + low4][ks * 32 + quad * 8];
            for (int i = 0; i < 2; ++i)
                for (int j = 0; j < 2; ++j)
                    acc[i][j] = MFMA16(a[i], b[j], acc[i][j]);
        }
    }

    for (int j = 0; j < 2; ++j) {
        int col = n0 + wn * 32 + j * 16 + low4;
        float bcol = bo[col];
        for (int i = 0; i < 2; ++i)
            for (int r = 0; r < 4; ++r) {
                int row = m0 + wm * 32 + i * 16 + quad * 4 + r;
                out[(size_t)row * D_MODEL + col] = acc[i][j][r] + bcol;
            }
    }
}

// ---------------------------------------------------------------------------
extern "C" void kernel_launch(void* const* d_in, const int* in_sizes, int n_in,
                              void* d_out, int out_size, void* d_ws, size_t ws_size,
                              hipStream_t stream)
{
    const float* q  = (const float*)d_in[0];
    const float* k  = (const float*)d_in[1];
    const float* v  = (const float*)d_in[2];
    const float* wq = (const float*)d_in[3];
    const float* bq = (const float*)d_in[4];
    const float* wk = (const float*)d_in[5];
    const float* bk = (const float*)d_in[6];
    const float* wv = (const float*)d_in[7];
    const float* bv = (const float*)d_in[8];
    const float* wo = (const float*)d_in[9];
    const float* bo = (const float*)d_in[10];

    const size_t NT = (size_t)NTOK * D_MODEL;
    bf16* Qh = (bf16*)d_ws;
    bf16* Kh = Qh + NT;
    bf16* Vt = Kh + NT;
    bf16* O  = Vt + NT;
    bf16* Wb = O + NT;                   // 4 x 512 x 512 bf16 = 2 MB

    cvt_w<<<1024, 256, 0, stream>>>(wq, wk, wv, wo, Wb);

    dim3 g1(NTOK / 128, D_MODEL / 128, 3);
    proj_qkv<<<g1, 256, 0, stream>>>(q, k, v, Wb, bq, bk, bv, Qh, Kh, Vt);

    attn<<<512, 256, 0, stream>>>(Qh, Kh, Vt, O);

    dim3 g3(NTOK / 64, D_MODEL / 64);
    proj_out<<<g3, 256, 0, stream>>>(O, Wb + (size_t)3 * D_MODEL * D_MODEL, bo, (float*)d_out);
}